// Round 1
// baseline (136.047 us; speedup 1.0000x reference)
//
#include <hip/hip_runtime.h>

#define D_DIM 8192
#define BK 256
#define NCHUNK (D_DIM / BK)   // 32
#define BN 32

typedef float f32x4 __attribute__((ext_vector_type(4)));
typedef short s16x8 __attribute__((ext_vector_type(8)));
typedef short s16x4 __attribute__((ext_vector_type(4)));

__device__ __forceinline__ unsigned short f2bf(float f) {
  union { float f; unsigned u; } v; v.f = f;
  return (unsigned short)((v.u + 0x7FFFu + ((v.u >> 16) & 1u)) >> 16);
}

// Stage one BK-chunk of x (32 batches) and W (32 rows) into registers.
#define ISSUE_LOADS(XS, WS, CH) do {                                            \
    const int k0_ = (CH) * BK;                                                  \
    _Pragma("unroll")                                                           \
    for (int i = 0; i < 8; ++i) {                                               \
      const int r_ = i * 4 + w;                                                 \
      XS[i] = *reinterpret_cast<const f32x4*>(                                  \
          x + (size_t)r_ * D_DIM + k0_ + c64 * 4);                              \
      WS[i] = *reinterpret_cast<const f32x4*>(                                  \
          wptr + (size_t)(erow0 + r_) * D_DIM + k0_ + c64 * 4);                 \
    } } while (0)

// Convert staged fp32 -> bf16 and write swizzled LDS buffer BUF.
#define CVT_WRITE(XS, WS, BUF) do {                                             \
    _Pragma("unroll")                                                           \
    for (int i = 0; i < 8; ++i) {                                               \
      const int r_ = i * 4 + w;                                                 \
      const int sc_ = (c64 * 4) ^ ((r_ & 7) << 3);                              \
      s16x4 xv_, wv_;                                                           \
      _Pragma("unroll")                                                         \
      for (int j = 0; j < 4; ++j) {                                             \
        xv_[j] = (short)f2bf(XS[i][j]);                                         \
        wv_[j] = (short)f2bf(WS[i][j]);                                         \
      }                                                                         \
      *reinterpret_cast<s16x4*>(&lds[BUF][0][r_ * BK + sc_]) = xv_;             \
      *reinterpret_cast<s16x4*>(&lds[BUF][1][r_ * BK + sc_]) = wv_;             \
    } } while (0)

// 8 K-steps of 32: read A/B fragments (swizzled) and MFMA.
#define MFMA_STEP(BUF) do {                                                     \
    _Pragma("unroll")                                                           \
    for (int ks = 0; ks < 8; ++ks) {                                            \
      const int ce_ = ks * 32 + kg;                                             \
      s16x8 av_ = *reinterpret_cast<const s16x8*>(                              \
          &lds[BUF][0][arow * BK + (ce_ ^ axor)]);                              \
      s16x8 bv_ = *reinterpret_cast<const s16x8*>(                              \
          &lds[BUF][1][brow * BK + (ce_ ^ bxor)]);                              \
      acc = __builtin_amdgcn_mfma_f32_16x16x32_bf16(av_, bv_, acc, 0, 0, 0);    \
    } } while (0)

__global__ __launch_bounds__(256, 2) void qkv_gemm(
    const float* __restrict__ x, const float* __restrict__ wq,
    const float* __restrict__ wk, const float* __restrict__ wv,
    float* __restrict__ out)
{
  // [buf][0=x / 1=w][row * BK + col], bf16 as ushort.  2*2*32*256*2B = 64 KiB
  __shared__ unsigned short lds[2][2][BN * BK];

  const int e0 = blockIdx.x * BN;
  const float* wptr;
  int outbase, erow0;
  if (e0 < 8192)      { wptr = wq; outbase = 0;      erow0 = e0; }
  else if (e0 < 9216) { wptr = wk; outbase = 262144; erow0 = e0 - 8192; }
  else                { wptr = wv; outbase = 294912; erow0 = e0 - 9216; }

  const int tid  = threadIdx.x;
  const int lane = tid & 63;
  const int w    = tid >> 6;     // wave 0..3
  const int c64  = tid & 63;     // float4 column within chunk

  // MFMA fragment addressing (wave quadrant of the 32x32 tile)
  const int wm   = w >> 1, wn = w & 1;
  const int arow = wm * 16 + (lane & 15);   // batch row
  const int brow = wn * 16 + (lane & 15);   // weight row (within tile)
  const int kg   = (lane >> 4) * 8;         // k-group offset
  const int axor = (arow & 7) << 3;
  const int bxor = (brow & 7) << 3;

  f32x4 acc = {0.f, 0.f, 0.f, 0.f};
  f32x4 xs0[8], ws0[8], xs1[8], ws1[8];

  ISSUE_LOADS(xs0, ws0, 0);
  ISSUE_LOADS(xs1, ws1, 1);

  for (int c = 0; c < NCHUNK; c += 2) {
    CVT_WRITE(xs0, ws0, 0);
    if (c + 2 < NCHUNK) ISSUE_LOADS(xs0, ws0, c + 2);
    __syncthreads();
    MFMA_STEP(0);

    CVT_WRITE(xs1, ws1, 1);
    if (c + 3 < NCHUNK) ISSUE_LOADS(xs1, ws1, c + 3);
    __syncthreads();
    MFMA_STEP(1);
  }

  // Epilogue: C/D layout col = lane&15 (N / weight row), row = (lane>>4)*4+r (M / batch)
  const int nloc  = wn * 16 + (lane & 15);
  const int er    = erow0 + nloc;
  const int obase = outbase + (er >> 7) * (32 * 128) + (er & 127);
  const int mb0   = wm * 16 + (lane >> 4) * 4;
  #pragma unroll
  for (int r = 0; r < 4; ++r)
    out[obase + (size_t)(mb0 + r) * 128] = acc[r];
}

extern "C" void kernel_launch(void* const* d_in, const int* in_sizes, int n_in,
                              void* d_out, int out_size, void* d_ws, size_t ws_size,
                              hipStream_t stream) {
  const float* x  = (const float*)d_in[0];
  const float* wq = (const float*)d_in[1];
  const float* wk = (const float*)d_in[2];
  const float* wv = (const float*)d_in[3];
  float* out = (float*)d_out;
  qkv_gemm<<<dim3(320), dim3(256), 0, stream>>>(x, wq, wk, wv, out);
}